// Round 2
// baseline (79.710 us; speedup 1.0000x reference)
//
#include <hip/hip_runtime.h>
#include <math.h>

#define NQ 10
#define BATCHN 8192
#define NF4 ((BATCHN * NQ) / 4)          // 20480 float4 in the input
#define BLK4 (256 * NQ / 4)              // 640 float4 per block's own chunk

// ---------------------------------------------------------------------------
// Analytic collapse of the circuit (verified against hand-computed sub-cases):
//
// State after encoding + ZZ layer: |psi> = (1/32) sum_j e^{i phi_j} |j>,
//   phi(s) = -pi*sum_q x_q s_q + pi*sum_{c<t} x_c x_t s_c s_t   (s_q = +/-1).
// Observable: <psi| E R'E' Rf' (-Z0) Rf E R E |psi>. Heisenberg conjugation
// through Rf, E, R, E yields 7 Pauli strings supported on qubits {0,1,2}.
// <Z0> = 0 (uniform magnitudes); for the rest Delta(phi) is linear in the
// unflipped spins, so the 1024-term sums factorize into cosine products:
//
// result = -g0 * sum_{m in {x0+x1, x0-x1}} S(m+w13) * C(m*x2)     * K(m)
//          +g1 * sum_{n in {x0+x2, x0-x2}} C(n+w13) * C(n*x1-w14) * K(n)
// with S/C = sin/cos(2pi * .), K(m) = prod_{t=3..9} C(m*x_t),
//      g0 = 0.5*cos(2pi(w0+w1+w2))*sin(2pi*w3), g1 = 0.5*sin(2pi(w0+w1+w2)).
// (w[4..12] and w[15..22] provably do not affect the output.)
//
// Single fused kernel: each block scans the WHOLE input for the global
// any(in>1) flag (removes the cross-kernel dependency; 32x redundant reads
// are L2/L3-absorbed) and stages its own 256x10 chunk to LDS on the way.
// v_sin_f32 / v_cos_f32 take input in revolutions, which matches the
// formulas above directly (all args are sums/products of atan-bounded
// values, well inside HW range-reduction limits).
// ---------------------------------------------------------------------------

__global__ __launch_bounds__(256) void fused_kernel(const float* __restrict__ in,
                                                    const float* __restrict__ w,
                                                    float* __restrict__ out) {
    __shared__ float xs[256 * NQ];
    __shared__ int bf;
    if (threadIdx.x == 0) bf = 0;
    __syncthreads();

    // ---- stage 1: global any(in > 1) scan + stage own chunk to LDS ----
    const float4* __restrict__ in4 = (const float4*)in;
    const int base4 = blockIdx.x * BLK4;
    float mx = -1.0f;
    for (int i = threadIdx.x; i < NF4; i += 256) {
        const float4 v = in4[i];
        mx = fmaxf(mx, fmaxf(fmaxf(v.x, v.y), fmaxf(v.z, v.w)));
        const unsigned d = (unsigned)(i - base4);
        if (d < (unsigned)BLK4) ((float4*)xs)[d] = v;
    }
    if (__any(mx > 1.0f) && (threadIdx.x & 63) == 0) atomicOr(&bf, 1);

    // ---- gate constants (uniform scalar loads + 3 HW trig; overlaps barrier) ----
    const float sw = w[0] + w[1] + w[2];
    const float g0 = 0.5f * __builtin_amdgcn_cosf(sw) * __builtin_amdgcn_sinf(w[3]);
    const float g1 = 0.5f * __builtin_amdgcn_sinf(sw);
    const float l0 = w[13], l1 = w[14];

    __syncthreads();
    const bool anyflag = (bf != 0);

    // ---- stage 2: per-element analytic expectation ----
    float x[NQ];
#pragma unroll
    for (int q = 0; q < NQ; ++q) x[q] = xs[threadIdx.x * NQ + q];
    if (anyflag) {
#pragma unroll
        for (int q = 0; q < NQ; ++q) x[q] = atanf(x[q]);
    }

    const float mp  = x[0] + x[1], mm = x[0] - x[1];   // F={0,1} combos
    const float np_ = x[0] + x[2], nm = x[0] - x[2];   // F={0,2} combos

    float Kmp = 1.0f, Kmm = 1.0f, Knp = 1.0f, Knm = 1.0f;
#pragma unroll
    for (int t = 3; t < NQ; ++t) {
        Kmp *= __builtin_amdgcn_cosf(mp * x[t]);
        Kmm *= __builtin_amdgcn_cosf(mm * x[t]);
        Knp *= __builtin_amdgcn_cosf(np_ * x[t]);
        Knm *= __builtin_amdgcn_cosf(nm * x[t]);
    }

    const float t1 = __builtin_amdgcn_sinf(mp + l0) * __builtin_amdgcn_cosf(mp * x[2]) * Kmp
                   + __builtin_amdgcn_sinf(mm + l0) * __builtin_amdgcn_cosf(mm * x[2]) * Kmm;
    const float t2 = __builtin_amdgcn_cosf(np_ + l0) * __builtin_amdgcn_cosf(np_ * x[1] - l1) * Knp
                   + __builtin_amdgcn_cosf(nm + l0) * __builtin_amdgcn_cosf(nm * x[1] - l1) * Knm;

    out[blockIdx.x * 256 + threadIdx.x] = fmaf(-g0, t1, g1 * t2);
}

extern "C" void kernel_launch(void* const* d_in, const int* in_sizes, int n_in,
                              void* d_out, int out_size, void* d_ws, size_t ws_size,
                              hipStream_t stream) {
    const float* inputs = (const float*)d_in[0];   // (8192, 10) float32
    const float* weight = (const float*)d_in[1];   // (23,) float32
    // d_in[2] = entangle_matrix — folded analytically (Clifford conjugation), unused.
    float* out = (float*)d_out;                    // (8192,) float32
    // d_ws unused.

    fused_kernel<<<BATCHN / 256, 256, 0, stream>>>(inputs, weight, out);
}

// Round 3
// 60.697 us; speedup vs baseline: 1.3132x; 1.3132x over previous
//
#include <hip/hip_runtime.h>
#include <math.h>

#define NQ 10
#define BATCHN 8192
#define NF4 ((BATCHN * NQ) / 4)     // 20480 float4 in the input
#define FLAGB (NF4 / 64)            // 320 one-wave flag blocks

// ---------------------------------------------------------------------------
// Analytic collapse of the circuit (verified against hand-computed sub-cases):
//
// State after encoding + ZZ layer: |psi> = (1/32) sum_j e^{i phi_j} |j>,
//   phi(s) = -pi*sum_q x_q s_q + pi*sum_{c<t} x_c x_t s_c s_t   (s_q = +/-1).
// Observable: <psi| E R'E' Rf' (-Z0) Rf E R E |psi>. Heisenberg conjugation
// through Rf, E, R, E yields 7 Pauli strings supported on qubits {0,1,2}.
// <Z0> = 0 (uniform magnitudes); for the rest Delta(phi) is linear in the
// unflipped spins, so the 1024-term sums factorize into cosine products:
//
// result = -g0 * sum_{m in {x0+x1, x0-x1}} S(m+w13) * C(m*x2)     * K(m)
//          +g1 * sum_{n in {x0+x2, x0-x2}} C(n+w13) * C(n*x1-w14) * K(n)
// with S/C = sin/cos(2pi * .), K(m) = prod_{t=3..9} C(m*x_t),
//      g0 = 0.5*cos(2pi(w0+w1+w2))*sin(2pi*w3), g1 = 0.5*sin(2pi(w0+w1+w2)).
// (w[4..12] and w[15..22] provably do not affect the output.)
//
// Two launches: the global any(in>1) flag is a grid-wide reduction that must
// complete before ANY output is written; an in-kernel spin-barrier is unsafe
// (workspace is re-poisoned each iteration, so no zero-initialized counter),
// and round-2 showed a per-block redundant whole-input scan is latency-bound
// (~35 us). Both kernels below are at their latency floor:
//   flag_kernel:   1 float4 load + wave-any + 1 store per thread. No LDS/loop.
//   expect_kernel: 5 independent float2 loads (own row) + 5 flag loads + trig.
//                  No LDS, no __syncthreads.
// ws layout: [0..319] int per-wave-block any(in>1) flags.
// ---------------------------------------------------------------------------

__global__ __launch_bounds__(64) void flag_kernel(const float* __restrict__ in,
                                                  int* __restrict__ flags) {
    const float4 v = ((const float4*)in)[blockIdx.x * 64 + threadIdx.x];
    const float mx = fmaxf(fmaxf(v.x, v.y), fmaxf(v.z, v.w));
    const int any = __any(mx > 1.0f) ? 1 : 0;
    if (threadIdx.x == 0) flags[blockIdx.x] = any;
}

__global__ __launch_bounds__(256) void expect_kernel(const float* __restrict__ in,
                                                     const int* __restrict__ flags,
                                                     const float* __restrict__ w,
                                                     float* __restrict__ out) {
    const int b    = blockIdx.x * 256 + threadIdx.x;
    const int lane = threadIdx.x & 63;

    // issue own-row loads first (5 independent float2, 8B-aligned, dense lines)
    const float2* __restrict__ r2 = (const float2*)in + (size_t)b * 5;
    const float2 p0 = r2[0], p1 = r2[1], p2 = r2[2], p3 = r2[3], p4 = r2[4];

    // global any(in>1): OR-reduce the 320 per-wave flags across the wave
    int f = flags[lane] | flags[lane + 64] | flags[lane + 128]
          | flags[lane + 192] | flags[lane + 256];
    const bool anyflag = __any(f != 0);

    // gate constants: uniform scalar loads + 3 HW trig (revolution units)
    const float sw = w[0] + w[1] + w[2];
    const float g0 = 0.5f * __builtin_amdgcn_cosf(sw) * __builtin_amdgcn_sinf(w[3]);
    const float g1 = 0.5f * __builtin_amdgcn_sinf(sw);
    const float l0 = w[13], l1 = w[14];

    float x[NQ] = {p0.x, p0.y, p1.x, p1.y, p2.x, p2.y, p3.x, p3.y, p4.x, p4.y};
    if (anyflag) {
#pragma unroll
        for (int q = 0; q < NQ; ++q) x[q] = atanf(x[q]);
    }

    const float mp  = x[0] + x[1], mm = x[0] - x[1];   // F={0,1} combos
    const float np_ = x[0] + x[2], nm = x[0] - x[2];   // F={0,2} combos

    float Kmp = 1.0f, Kmm = 1.0f, Knp = 1.0f, Knm = 1.0f;
#pragma unroll
    for (int t = 3; t < NQ; ++t) {
        Kmp *= __builtin_amdgcn_cosf(mp * x[t]);
        Kmm *= __builtin_amdgcn_cosf(mm * x[t]);
        Knp *= __builtin_amdgcn_cosf(np_ * x[t]);
        Knm *= __builtin_amdgcn_cosf(nm * x[t]);
    }

    const float t1 = __builtin_amdgcn_sinf(mp + l0) * __builtin_amdgcn_cosf(mp * x[2]) * Kmp
                   + __builtin_amdgcn_sinf(mm + l0) * __builtin_amdgcn_cosf(mm * x[2]) * Kmm;
    const float t2 = __builtin_amdgcn_cosf(np_ + l0) * __builtin_amdgcn_cosf(np_ * x[1] - l1) * Knp
                   + __builtin_amdgcn_cosf(nm + l0) * __builtin_amdgcn_cosf(nm * x[1] - l1) * Knm;

    out[b] = fmaf(-g0, t1, g1 * t2);
}

extern "C" void kernel_launch(void* const* d_in, const int* in_sizes, int n_in,
                              void* d_out, int out_size, void* d_ws, size_t ws_size,
                              hipStream_t stream) {
    const float* inputs = (const float*)d_in[0];   // (8192, 10) float32
    const float* weight = (const float*)d_in[1];   // (23,) float32
    // d_in[2] = entangle_matrix — folded analytically (Clifford conjugation), unused.
    float* out   = (float*)d_out;                  // (8192,) float32
    int*   flags = (int*)d_ws;                     // 320 ints (rewritten every launch)

    flag_kernel<<<FLAGB, 64, 0, stream>>>(inputs, flags);
    expect_kernel<<<BATCHN / 256, 256, 0, stream>>>(inputs, flags, weight, out);
}